// Round 4
// baseline (318.378 us; speedup 1.0000x reference)
//
#include <hip/hip_runtime.h>
#include <math.h>
#include <limits.h>

#define B_  8
#define L_  128
#define VF_ 32128
#define V_  32100
#define D_  768

#define SEGS_ 2
#define NV4_  (VF_ / 4)   // 8032 float4s per row
#define HALF_ (NV4_ / 2)  // 4016 float4s per half-row

typedef unsigned long long u64;
typedef float f4v __attribute__((ext_vector_type(4)));

// Monotone map: f1 > f2  <=>  fmap(f1) > fmap(f2)  (inputs have no NaNs)
__device__ __forceinline__ unsigned int fmap(float f) {
    unsigned int u = __float_as_uint(f);
    return (u & 0x80000000u) ? ~u : (u | 0x80000000u);
}

// Scan 16 strided chunks; NT selects the gumbel load flavor at compile time.
// NT=false: allocating load (line becomes/stays L3-resident across launches).
// NT=true : nontemporal (no L3 allocation; pure HBM stream).
template <bool NT>
__device__ __forceinline__ void scan_half(
    const f4v* __restrict__ lp, const f4v* __restrict__ gp,
    int i, float& bv, int& bi)
{
    #pragma unroll 4
    for (int it = 0; it < 16; ++it) {
        const int ii = (i < NV4_ - 1) ? i : (NV4_ - 1);
        const f4v a = lp[ii];
        const f4v g = NT ? __builtin_nontemporal_load(gp + ii) : gp[ii];
        float v;
        v = a[0] + g[0]; if (v > bv) { bv = v; bi = 4*ii + 0; }
        v = a[1] + g[1]; if (v > bv) { bv = v; bi = 4*ii + 1; }
        v = a[2] + g[2]; if (v > bv) { bv = v; bi = 4*ii + 2; }
        v = a[3] + g[3]; if (v > bv) { bv = v; bi = 4*ii + 3; }
        i += 256;
    }
}

// ---------------------------------------------------------------------------
// Kernel 1: segment argmax of logits+gumbel, streaming-loop shape.
// Grid = 1024 rows x 2 halves = 2048 blocks, 256 threads, (256,8).
// TIER SPLIT (round-4 single-variable change): logits (131 MB) is already
// L3-resident (R3 evidence: FETCH==gumbel only). L3 headroom ~58 MB ->
// make gumbel's FIRST half allocating too (66 MB, resident across
// launches); second half stays nontemporal. Resident set ~205 MB < 256.
// Per-launch HBM traffic should drop 130 -> ~66 MB.
// Keys carry GLOBAL indices so duplicated candidates merge under max.
// ---------------------------------------------------------------------------
__global__ __launch_bounds__(256, 8) void k_argmax(
    const float* __restrict__ logits, const float* __restrict__ gumbel,
    u64* __restrict__ keys)
{
    const int row  = blockIdx.x >> 1;           // 0..1023
    const int half = blockIdx.x & 1;            // 0..1
    const int tid  = threadIdx.x;               // 0..255
    const size_t rowoff = (size_t)row * VF_;
    const f4v* lp = (const f4v*)(logits + rowoff);
    const f4v* gp = (const f4v*)(gumbel + rowoff);

    float bv = -INFINITY;
    int   bi = 0;
    const int i0 = half * HALF_ + tid;
    if (half == 0) scan_half<false>(lp, gp, i0, bv, bi);  // resident tier
    else           scan_half<true >(lp, gp, i0, bv, bi);  // HBM-stream tier

    // bigger value wins; equal value -> smaller idx (larger VF-idx) wins
    u64 k = ((u64)fmap(bv) << 32) | (u64)(VF_ - bi);
    for (int off = 32; off > 0; off >>= 1) {
        u64 o = __shfl_down(k, off, 64);
        if (o > k) k = o;
    }
    __shared__ u64 s_k[4];
    if ((tid & 63) == 0) s_k[tid >> 6] = k;
    __syncthreads();
    if (tid == 0) {
        u64 kk = s_k[0];
        if (s_k[1] > kk) kk = s_k[1];
        if (s_k[2] > kk) kk = s_k[2];
        if (s_k[3] > kk) kk = s_k[3];
        keys[blockIdx.x] = kk;
    }
}

// ---------------------------------------------------------------------------
// Kernel 2 (fused): per-(b,l) block. Merges the row's 2 segment keys,
// redundantly recomputes the per-b control logic (cheap: 256 int loads),
// then gathers the W row(s) into the output. 192 threads (768 floats / f4).
// ---------------------------------------------------------------------------
__global__ __launch_bounds__(192) void k_emb(
    const float* __restrict__ W,
    const int* __restrict__ rwrt, const int* __restrict__ psg,
    const u64* __restrict__ keys,
    float* __restrict__ out, float* __restrict__ nn_out)
{
    const int row = blockIdx.x;          // b*128 + l
    const int b = row >> 7;
    const int l = row & 127;
    const int t = threadIdx.x;           // 0..191

    __shared__ int s_att[L_];
    __shared__ int s_extr[L_];
    __shared__ u64 s_keys[SEGS_];
    __shared__ int s_len, s_first, s_rA, s_rB;

    if (t == 0) s_first = INT_MAX;
    if (t < L_) s_att[t] = rwrt[b * L_ + t];
    if (t >= 128 && t < 128 + SEGS_) s_keys[t - 128] = keys[row * SEGS_ + (t - 128)];
    __syncthreads();

    if (t == 0) {
        int len = 0;
        for (int i = 0; i < L_; ++i) len += (s_att[i] == 1);
        s_len = len;
    }
    if (t < L_) s_extr[t] = (1 - s_att[L_ - 1 - t]) * psg[b * L_ + t];
    __syncthreads();

    if (t < L_) {
        int src = (t - s_len + L_) & (L_ - 1);
        if (s_extr[src] != 0) atomicMin(&s_first, t);
    }
    __syncthreads();

    if (t == 0) {
        u64 kk = s_keys[0];
        #pragma unroll
        for (int i = 1; i < SEGS_; ++i) if (s_keys[i] > kk) kk = s_keys[i];
        const int am   = VF_ - (int)(kk & 0xFFFFFFFFull);
        const int srcl = (l - s_len + L_) & (L_ - 1);
        const int idxv = s_extr[srcl];
        const int flag = (l >= s_first) ? 1 : 0;
        const int rA = (s_att[l] == 1 && am < V_) ? am : -1;
        const int rB = flag ? idxv : -1;
        s_rA = rA; s_rB = rB;
        // Every realized row is exactly one W row (or zero): nn = its index.
        // Zero row -> all-zero sims -> jnp.argmax ties to 0.
        const int nn = (rA >= 0) ? rA : ((rB >= 0) ? rB : 0);
        nn_out[row] = (float)nn;
    }
    __syncthreads();

    const int rA = s_rA;
    const int rB = s_rB;
    float4 v = make_float4(0.f, 0.f, 0.f, 0.f);
    if (rA >= 0) {
        float4 a = ((const float4*)(W + (size_t)rA * D_))[t];
        v.x += a.x; v.y += a.y; v.z += a.z; v.w += a.w;
    }
    if (rB >= 0) {
        float4 a = ((const float4*)(W + (size_t)rB * D_))[t];
        v.x += a.x; v.y += a.y; v.z += a.z; v.w += a.w;
    }
    ((float4*)(out + (size_t)row * D_))[t] = v;
}

extern "C" void kernel_launch(void* const* d_in, const int* in_sizes, int n_in,
                              void* d_out, int out_size, void* d_ws, size_t ws_size,
                              hipStream_t stream)
{
    const float* logits = (const float*)d_in[0];
    const float* gumbel = (const float*)d_in[1];
    const float* W      = (const float*)d_in[2];
    const int*   rwrt   = (const int*)d_in[3];
    const int*   psg    = (const int*)d_in[4];

    float* out    = (float*)d_out;                       // embeds: 8*128*768
    float* nn_out = out + (size_t)B_ * L_ * D_;          // nn_idx as float: 1024

    u64* keys = (u64*)d_ws;                  // 2048 u64 segment keys (16 KB)

    k_argmax<<<B_ * L_ * SEGS_, 256, 0, stream>>>(logits, gumbel, keys);
    k_emb<<<B_ * L_, 192, 0, stream>>>(W, rwrt, psg, keys, out, nn_out);
}

// Round 5
// 308.996 us; speedup vs baseline: 1.0304x; 1.0304x over previous
//
#include <hip/hip_runtime.h>
#include <math.h>
#include <limits.h>

#define B_  8
#define L_  128
#define VF_ 32128
#define V_  32100
#define D_  768

#define SEGS_ 2
#define NV4_  (VF_ / 4)   // 8032 float4s per row
#define HALF_ (NV4_ / 2)  // 4016 float4s per half-row

typedef unsigned long long u64;
typedef float f4 __attribute__((ext_vector_type(4)));
typedef const __attribute__((address_space(1))) void* as1p;
typedef __attribute__((address_space(3))) void* as3p;

// Monotone map: f1 > f2  <=>  fmap(f1) > fmap(f2)  (inputs have no NaNs)
__device__ __forceinline__ unsigned int fmap(float f) {
    unsigned int u = __float_as_uint(f);
    return (u & 0x80000000u) ? ~u : (u | 0x80000000u);
}

// ---------------------------------------------------------------------------
// Kernel 1: segment argmax of logits+gumbel via DEEP ASYNC LDS-DMA pipeline.
// Grid = 1024 rows x 2 halves = 2048 blocks, 256 threads, (256,5).
// Per wave, per iter: 2x global_load_lds (16B/lane, 1KB/wave/stream) into a
// PRIVATE per-wave LDS slot; 4 iters (8 DMAs) kept in flight via counted
// s_waitcnt vmcnt(6) -- no __syncthreads in the hot loop, so no barrier
// drain. Read-back via inline-asm ds_read_b128 with the vmcnt/lgkmcnt waits
// folded INSIDE the asm (data-dep ordered; invisible to the compiler's
// conservative LDS-DMA waitcnt pass). Cache policy = R3's proven winner:
// logits allocating (L3-resident), gumbel nt (aux=2 -> no L3 pollution).
// LDS 32KB/block -> 5 blocks/CU (20 waves). Keys carry GLOBAL indices.
// ---------------------------------------------------------------------------
__global__ __launch_bounds__(256, 5) void k_argmax(
    const float* __restrict__ logits, const float* __restrict__ gumbel,
    u64* __restrict__ keys)
{
    // Layout: [slot 0..3][stream 0..1][wave 0..3][lane 0..63] float4
    // slot stride 8192 B, stream stride 4096 B, wave stride 1024 B.
    __shared__ char lds_raw[32768];

    const int row  = blockIdx.x >> 1;           // 0..1023
    const int half = blockIdx.x & 1;            // 0..1
    const int tid  = threadIdx.x;               // 0..255
    const int w    = tid >> 6;                  // wave 0..3
    const int lane = tid & 63;
    const size_t rowoff = (size_t)row * VF_;
    const float* lpf = logits + rowoff;
    const float* gpf = gumbel + rowoff;
    const int cbase = half * HALF_ + w * 64;    // wave chunk base (float4 idx)
    const unsigned woff  = (unsigned)(w * 1024);
    const unsigned lbase = (unsigned)(size_t)(__attribute__((address_space(3))) char*)lds_raw;

#define ISSUE(j) do {                                                         \
    const int i_ = cbase + (j)*256 + lane;                                    \
    const int ii_ = (i_ < NV4_-1) ? i_ : (NV4_-1);                            \
    const unsigned so_ = (unsigned)(((j)&3)*8192) + woff;                     \
    __builtin_amdgcn_global_load_lds((as1p)(lpf + (size_t)ii_*4),             \
                                     (as3p)(lds_raw + so_),        16, 0, 0); \
    __builtin_amdgcn_global_load_lds((as1p)(gpf + (size_t)ii_*4),             \
                                     (as3p)(lds_raw + so_ + 4096), 16, 0, 2); \
} while (0)

#define CONSUME(it, K) do {                                                   \
    f4 aL, aG;                                                                \
    const unsigned off_ = lbase + (unsigned)(((it)&3)*8192) + woff            \
                        + (unsigned)(lane*16);                                \
    asm volatile("s_waitcnt vmcnt(" #K ")\n\t"                                \
                 "ds_read_b128 %0, %2\n\t"                                    \
                 "ds_read_b128 %1, %2 offset:4096\n\t"                        \
                 "s_waitcnt lgkmcnt(0)"                                       \
                 : "=v"(aL), "=v"(aG) : "v"(off_) : "memory");                \
    const int i_ = cbase + (it)*256 + lane;                                   \
    const int ii_ = (i_ < NV4_-1) ? i_ : (NV4_-1);                            \
    float v_;                                                                 \
    v_ = aL[0]+aG[0]; if (v_>bv){bv=v_; bi=4*ii_+0;}                          \
    v_ = aL[1]+aG[1]; if (v_>bv){bv=v_; bi=4*ii_+1;}                          \
    v_ = aL[2]+aG[2]; if (v_>bv){bv=v_; bi=4*ii_+2;}                          \
    v_ = aL[3]+aG[3]; if (v_>bv){bv=v_; bi=4*ii_+3;}                          \
} while (0)

    float bv = -INFINITY;
    int   bi = 0;

    ISSUE(0); ISSUE(1); ISSUE(2); ISSUE(3);
    CONSUME(0, 6);  ISSUE(4);
    CONSUME(1, 6);  ISSUE(5);
    CONSUME(2, 6);  ISSUE(6);
    CONSUME(3, 6);  ISSUE(7);
    CONSUME(4, 6);  ISSUE(8);
    CONSUME(5, 6);  ISSUE(9);
    CONSUME(6, 6);  ISSUE(10);
    CONSUME(7, 6);  ISSUE(11);
    CONSUME(8, 6);  ISSUE(12);
    CONSUME(9, 6);  ISSUE(13);
    CONSUME(10, 6); ISSUE(14);
    CONSUME(11, 6); ISSUE(15);
    CONSUME(12, 6);
    CONSUME(13, 4);
    CONSUME(14, 2);
    CONSUME(15, 0);
#undef ISSUE
#undef CONSUME

    // bigger value wins; equal value -> smaller idx (larger VF-idx) wins
    u64 k = ((u64)fmap(bv) << 32) | (u64)(VF_ - bi);
    for (int off = 32; off > 0; off >>= 1) {
        u64 o = __shfl_down(k, off, 64);
        if (o > k) k = o;
    }
    // All waves' DMAs are retired (own vmcnt(0) at CONSUME 15) before the
    // barrier; then reuse the first 32 B of lds_raw for the cross-wave merge.
    __syncthreads();
    u64* s_k = (u64*)lds_raw;
    if (lane == 0) s_k[w] = k;
    __syncthreads();
    if (tid == 0) {
        u64 kk = s_k[0];
        if (s_k[1] > kk) kk = s_k[1];
        if (s_k[2] > kk) kk = s_k[2];
        if (s_k[3] > kk) kk = s_k[3];
        keys[blockIdx.x] = kk;
    }
}

// ---------------------------------------------------------------------------
// Kernel 2 (fused): per-(b,l) block. Merges the row's 2 segment keys,
// redundantly recomputes the per-b control logic (cheap: 256 int loads),
// then gathers the W row(s) into the output. 192 threads (768 floats / f4).
// ---------------------------------------------------------------------------
__global__ __launch_bounds__(192) void k_emb(
    const float* __restrict__ W,
    const int* __restrict__ rwrt, const int* __restrict__ psg,
    const u64* __restrict__ keys,
    float* __restrict__ out, float* __restrict__ nn_out)
{
    const int row = blockIdx.x;          // b*128 + l
    const int b = row >> 7;
    const int l = row & 127;
    const int t = threadIdx.x;           // 0..191

    __shared__ int s_att[L_];
    __shared__ int s_extr[L_];
    __shared__ u64 s_keys[SEGS_];
    __shared__ int s_len, s_first, s_rA, s_rB;

    if (t == 0) s_first = INT_MAX;
    if (t < L_) s_att[t] = rwrt[b * L_ + t];
    if (t >= 128 && t < 128 + SEGS_) s_keys[t - 128] = keys[row * SEGS_ + (t - 128)];
    __syncthreads();

    if (t == 0) {
        int len = 0;
        for (int i = 0; i < L_; ++i) len += (s_att[i] == 1);
        s_len = len;
    }
    if (t < L_) s_extr[t] = (1 - s_att[L_ - 1 - t]) * psg[b * L_ + t];
    __syncthreads();

    if (t < L_) {
        int src = (t - s_len + L_) & (L_ - 1);
        if (s_extr[src] != 0) atomicMin(&s_first, t);
    }
    __syncthreads();

    if (t == 0) {
        u64 kk = s_keys[0];
        #pragma unroll
        for (int i = 1; i < SEGS_; ++i) if (s_keys[i] > kk) kk = s_keys[i];
        const int am   = VF_ - (int)(kk & 0xFFFFFFFFull);
        const int srcl = (l - s_len + L_) & (L_ - 1);
        const int idxv = s_extr[srcl];
        const int flag = (l >= s_first) ? 1 : 0;
        const int rA = (s_att[l] == 1 && am < V_) ? am : -1;
        const int rB = flag ? idxv : -1;
        s_rA = rA; s_rB = rB;
        // Every realized row is exactly one W row (or zero): nn = its index.
        // Zero row -> all-zero sims -> jnp.argmax ties to 0.
        const int nn = (rA >= 0) ? rA : ((rB >= 0) ? rB : 0);
        nn_out[row] = (float)nn;
    }
    __syncthreads();

    const int rA = s_rA;
    const int rB = s_rB;
    float4 v = make_float4(0.f, 0.f, 0.f, 0.f);
    if (rA >= 0) {
        float4 a = ((const float4*)(W + (size_t)rA * D_))[t];
        v.x += a.x; v.y += a.y; v.z += a.z; v.w += a.w;
    }
    if (rB >= 0) {
        float4 a = ((const float4*)(W + (size_t)rB * D_))[t];
        v.x += a.x; v.y += a.y; v.z += a.z; v.w += a.w;
    }
    ((float4*)(out + (size_t)row * D_))[t] = v;
}

extern "C" void kernel_launch(void* const* d_in, const int* in_sizes, int n_in,
                              void* d_out, int out_size, void* d_ws, size_t ws_size,
                              hipStream_t stream)
{
    const float* logits = (const float*)d_in[0];
    const float* gumbel = (const float*)d_in[1];
    const float* W      = (const float*)d_in[2];
    const int*   rwrt   = (const int*)d_in[3];
    const int*   psg    = (const int*)d_in[4];

    float* out    = (float*)d_out;                       // embeds: 8*128*768
    float* nn_out = out + (size_t)B_ * L_ * D_;          // nn_idx as float: 1024

    u64* keys = (u64*)d_ws;                  // 2048 u64 segment keys (16 KB)

    k_argmax<<<B_ * L_ * SEGS_, 256, 0, stream>>>(logits, gumbel, keys);
    k_emb<<<B_ * L_, 192, 0, stream>>>(W, rwrt, psg, keys, out, nn_out);
}